// Round 1
// baseline (270.467 us; speedup 1.0000x reference)
//
#include <hip/hip_runtime.h>

// logeig(M) for SPD M = A A^T/64 + I; spectrum in [1,~6.6]; w = (M-4.7I)/3.8.
// Deg-11 poly of log via PS s=2 Horner: T=q5; T = T*W2 + q_s (s=4..0).
// Each 64x64 matmul emulated with 3x bf16 MFMA (hi=trunc16, lo=RNE remainder).
//
// NEW STRUCTURE (vs 306us baseline): one wave == one matrix, ZERO barriers
// after P0, zero LDS round-trips in the Horner loop. The C-layout -> A/B-frag
// "transpose" uses symmetry: frag[t][kb] elem e = T[16kb+8h+e][32t+ln], held
// by lane (ln | (e>=4)<<5) at acc reg (e&3)+4*(h+2*(kb&1)) of tile (kb>>1,t).
// One v_permlane32_swap_b32 per packed bf16 pair redistributes the h-halves
// (swap(X0,X1): out0 = both low-lane halves, out1 = both high-lane halves).
// LDS holds only the fp32 w plane (16 KB, rotation 4*(row&7) for bank spread):
// consumed by P1 w-frags and the per-step q_s init. 8 blocks/CU, 2 waves/SIMD.

typedef __attribute__((ext_vector_type(8)))  __bf16       bfrag;  // 4 VGPR
typedef __attribute__((ext_vector_type(16))) float        facc;   // 16 VGPR
typedef __attribute__((ext_vector_type(4)))  unsigned int uint4v;

#define MFMA(a, b, c) __builtin_amdgcn_mfma_f32_32x32x16_bf16((a), (b), (c), 0, 0, 0)

static __device__ __forceinline__ void plswap(unsigned& a, unsigned& b) {
    auto r = __builtin_amdgcn_permlane32_swap(a, b, false, false);
    a = (unsigned)r[0];  // {a lanes 0-31, b lanes 0-31}
    b = (unsigned)r[1];  // {a lanes 32-63, b lanes 32-63}
}
static __device__ __forceinline__ unsigned cvtpk(float lo, float hi) {
    unsigned r;  // RNE pack: low16 = bf16(lo), high16 = bf16(hi)
    asm("v_cvt_pk_bf16_f32 %0, %1, %2" : "=v"(r) : "v"(lo), "v"(hi));
    return r;
}

// fp32 plane: S[p][q] at p*64 + ((q + 4*(p&7)) & 63); quads stay 16B-aligned
// and never straddle the mod-64 wrap (q0 mult of 4).
static __device__ __forceinline__ float4 ld4(const float* pl, int p, int q0) {
    int idx = (p << 6) + ((q0 + ((p & 7) << 2)) & 63);
    return *(const float4*)(pl + idx);
}

// acc tile (kb>>1, t) -> hi/lo bf16 A/B-frag for (t, kb), fully in-register.
static __device__ __forceinline__ void build_frag(const facc& a, int b,
                                                  bfrag& fh, bfrag& fl) {
    unsigned Ph[2][2], Pl[2][2];  // [h_sub][pair]
#pragma unroll
    for (int hs = 0; hs < 2; ++hs)
#pragma unroll
        for (int p = 0; p < 2; ++p) {
            int r0 = ((hs + 2 * b) << 2) + (p << 1);
            float x = a[r0], y = a[r0 + 1];
            unsigned ux = __float_as_uint(x), uy = __float_as_uint(y);
            Ph[hs][p] = (ux >> 16) | (uy & 0xFFFF0000u);
            float rx = x - __uint_as_float(ux & 0xFFFF0000u);
            float ry = y - __uint_as_float(uy & 0xFFFF0000u);
            Pl[hs][p] = cvtpk(rx, ry);
        }
#pragma unroll
    for (int p = 0; p < 2; ++p) {
        plswap(Ph[0][p], Ph[1][p]);  // Ph[0]=elems e<4, Ph[1]=elems e>=4
        plswap(Pl[0][p], Pl[1][p]);
    }
    uint4v uh, ul;
    uh[0] = Ph[0][0]; uh[1] = Ph[0][1]; uh[2] = Ph[1][0]; uh[3] = Ph[1][1];
    ul[0] = Pl[0][0]; ul[1] = Pl[0][1]; ul[2] = Pl[1][0]; ul[3] = Pl[1][1];
    fh = __builtin_bit_cast(bfrag, uh);
    fl = __builtin_bit_cast(bfrag, ul);
}

__global__ void __launch_bounds__(64, 2)
logeig_mfma_kernel(const float* __restrict__ in, float* __restrict__ out) {
    // monomial coeffs of deg-11 Chebyshev fit of log on [0.9, 8.5] in w
    constexpr float Bc[12] = {1.547606f,  0.808267f,  -0.329629f, 0.182560f,
                              -0.077085f, 0.022485f,  -0.158573f, 0.172463f,
                              0.154589f,  -0.173671f, -0.119491f, 0.110580f};

    __shared__ __align__(16) float w32[4096];  // 16 KB fp32 w plane

    const int l   = threadIdx.x;
    const int h   = l >> 5;
    const int ln  = l & 31;
    const int lnh = ln - (h << 2);  // diag test: 8*qd + k == lnh

    const size_t mat = blockIdx.x;
    const float* g  = in  + (mat << 12);
    float*       go = out + (mat << 12);

    // ---- P0: load M (coalesced float4), w = (M - 4.7 I)/3.8 -> fp32 plane.
#pragma unroll
    for (int rep = 0; rep < 16; ++rep) {
        int f = l + (rep << 6);
        int r = f >> 4, c4 = (f & 15) << 2;
        float4 v = ((const float4*)g)[f];
        float4 wv;
        wv.x = (v.x - ((r == c4 + 0) ? 4.7f : 0.0f)) * (1.0f / 3.8f);
        wv.y = (v.y - ((r == c4 + 1) ? 4.7f : 0.0f)) * (1.0f / 3.8f);
        wv.z = (v.z - ((r == c4 + 2) ? 4.7f : 0.0f)) * (1.0f / 3.8f);
        wv.w = (v.w - ((r == c4 + 3) ? 4.7f : 0.0f)) * (1.0f / 3.8f);
        int idx = (r << 6) + ((c4 + ((r & 7) << 2)) & 63);
        *(float4*)(w32 + idx) = wv;
    }
    __syncthreads();  // single-wave block: trivial, just orders LDS

    // ---- w frags (hi/lo) for P1: read own rows from plane, split in regs.
    bfrag wfh[2][4], wfl[2][4];
#pragma unroll
    for (int t = 0; t < 2; ++t)
#pragma unroll
        for (int kb = 0; kb < 4; ++kb) {
            int row = (t << 5) + ln, q0 = (kb << 4) + (h << 3);
            float4 v0 = ld4(w32, row, q0);
            float4 v1 = ld4(w32, row, q0 + 4);
            float e[8] = {v0.x, v0.y, v0.z, v0.w, v1.x, v1.y, v1.z, v1.w};
            uint4v uh, ul;
#pragma unroll
            for (int j = 0; j < 4; ++j) {
                unsigned ux = __float_as_uint(e[2 * j]);
                unsigned uy = __float_as_uint(e[2 * j + 1]);
                uh[j] = (ux >> 16) | (uy & 0xFFFF0000u);
                float rx = e[2 * j]     - __uint_as_float(ux & 0xFFFF0000u);
                float ry = e[2 * j + 1] - __uint_as_float(uy & 0xFFFF0000u);
                ul[j] = cvtpk(rx, ry);
            }
            wfh[t][kb] = __builtin_bit_cast(bfrag, uh);
            wfl[t][kb] = __builtin_bit_cast(bfrag, ul);
        }

    // ---- P1: W2 = w*w (hh + hl + lh), all 4 tiles owned by this wave.
    facc c[2][2];
#pragma unroll
    for (int ti = 0; ti < 2; ++ti)
#pragma unroll
        for (int tj = 0; tj < 2; ++tj) c[ti][tj] = (facc)0.0f;
#pragma unroll
    for (int kb = 0; kb < 4; ++kb)
#pragma unroll
        for (int ti = 0; ti < 2; ++ti) {
            bfrag ah = wfh[ti][kb], al = wfl[ti][kb];
#pragma unroll
            for (int tj = 0; tj < 2; ++tj) {
                c[ti][tj] = MFMA(ah, wfh[tj][kb], c[ti][tj]);
                c[ti][tj] = MFMA(ah, wfl[tj][kb], c[ti][tj]);
                c[ti][tj] = MFMA(al, wfh[tj][kb], c[ti][tj]);
            }
        }

    // ---- W2 B-frags via in-register permlane transpose; persistent.
    bfrag W2h[2][4], W2l[2][4];
#pragma unroll
    for (int kb = 0; kb < 4; ++kb)
#pragma unroll
        for (int tj = 0; tj < 2; ++tj)
            build_frag(c[kb >> 1][tj], kb & 1, W2h[tj][kb], W2l[tj][kb]);

    // ---- T = q5 = Bc[10] I + Bc[11] w  (C-layout init from fp32 plane).
    facc T[2][2];
#pragma unroll
    for (int ti = 0; ti < 2; ++ti)
#pragma unroll
        for (int tj = 0; tj < 2; ++tj) {
            int col = (tj << 5) + ln;
#pragma unroll
            for (int qd = 0; qd < 4; ++qd) {
                int qb = (ti << 5) + (qd << 3) + (h << 2);
                float4 v = ld4(w32, col, qb);  // w[qb+k][col] via symmetry
                float e4[4] = {v.x, v.y, v.z, v.w};
#pragma unroll
                for (int k = 0; k < 4; ++k) {
                    float dia = (ti == tj && ((qd << 3) + k) == lnh) ? Bc[10] : 0.0f;
                    T[ti][tj][(qd << 2) + k] = fmaf(Bc[11], e4[k], dia);
                }
            }
        }

    // ---- Horner s=4..0: d = q_s + T*W2. No LDS round-trip, no barriers.
#pragma unroll
    for (int s = 4; s >= 0; --s) {
        const float kI = Bc[2 * s], kw = Bc[2 * s + 1];
        facc d[2][2];
#pragma unroll
        for (int ti = 0; ti < 2; ++ti)
#pragma unroll
            for (int tj = 0; tj < 2; ++tj) {
                int col = (tj << 5) + ln;
#pragma unroll
                for (int qd = 0; qd < 4; ++qd) {
                    int qb = (ti << 5) + (qd << 3) + (h << 2);
                    float4 v = ld4(w32, col, qb);
                    float e4[4] = {v.x, v.y, v.z, v.w};
#pragma unroll
                    for (int k = 0; k < 4; ++k) {
                        float dia = (ti == tj && ((qd << 3) + k) == lnh) ? kI : 0.0f;
                        d[ti][tj][(qd << 2) + k] = fmaf(kw, e4[k], dia);
                    }
                }
            }
#pragma unroll
        for (int kb = 0; kb < 4; ++kb)
#pragma unroll
            for (int ti = 0; ti < 2; ++ti) {
                bfrag th, tl;
                build_frag(T[kb >> 1][ti], kb & 1, th, tl);
#pragma unroll
                for (int tj = 0; tj < 2; ++tj) {
                    d[ti][tj] = MFMA(th, W2h[tj][kb], d[ti][tj]);
                    d[ti][tj] = MFMA(th, W2l[tj][kb], d[ti][tj]);
                    d[ti][tj] = MFMA(tl, W2h[tj][kb], d[ti][tj]);
                }
            }
        if (s > 0) {
#pragma unroll
            for (int ti = 0; ti < 2; ++ti)
#pragma unroll
                for (int tj = 0; tj < 2; ++tj) T[ti][tj] = d[ti][tj];
        } else {
            // out = T: C-layout straight to global (two 128B segments/instr)
#pragma unroll
            for (int ti = 0; ti < 2; ++ti)
#pragma unroll
                for (int tj = 0; tj < 2; ++tj)
#pragma unroll
                    for (int reg = 0; reg < 16; ++reg) {
                        int row = (ti << 5) + (reg & 3) + ((reg >> 2) << 3) + (h << 2);
                        go[(row << 6) + (tj << 5) + ln] = d[ti][tj][reg];
                    }
        }
    }
}

extern "C" void kernel_launch(void* const* d_in, const int* in_sizes, int n_in,
                              void* d_out, int out_size, void* d_ws, size_t ws_size,
                              hipStream_t stream) {
    const float* in = (const float*)d_in[0];
    float* out = (float*)d_out;
    const int batch = in_sizes[0] >> 12;  // 8192 matrices of 64x64
    hipLaunchKernelGGL(logeig_mfma_kernel, dim3(batch), dim3(64), 0,
                       stream, in, out);
}

// Round 3
// 244.980 us; speedup vs baseline: 1.1040x; 1.1040x over previous
//
#include <hip/hip_runtime.h>

// logeig(M) for SPD M = A A^T/64 + I; spectrum in [1,~6.6]; w = (M-4.7I)/3.8.
// Deg-11 poly of log via PS s=2 Horner: T=q5; T = T*W2 + q_s (s=4..0).
// One wave == one matrix, zero barriers after P0, all state in registers.
//
// f16 EMULATION (vs bf16 3-term): T split hi+lo f16 (exact to 2^-22),
// W2 as a SINGLE RNE-rounded f16 frag -> 2 MFMA per product (was 3), and
// only 32 persistent W2 VGPRs (was 64). P1 (W2=w*w) keeps 3-term hi/lo for
// near-exact W2 before its one rounding. C-layout -> A/B-frag transpose via
// symmetry + v_permlane32_swap (1 per packed pair). LDS: 16 KB fp32 w plane
// (rotation 4*(row&7)) feeds P1 frags and per-step q_s = kI*I + kw*w; diag
// handled by a one-hot dvec[16] fma (no per-step cmp/cndmask).

typedef __attribute__((ext_vector_type(8)))  __fp16       hfrag;  // 4 VGPR
typedef __attribute__((ext_vector_type(2)))  __fp16       half2v;
typedef __attribute__((ext_vector_type(16))) float        facc;   // 16 VGPR
typedef __attribute__((ext_vector_type(4)))  unsigned int uint4v;

#define MFMA(a, b, c) __builtin_amdgcn_mfma_f32_32x32x16_f16((a), (b), (c), 0, 0, 0)

static __device__ __forceinline__ void plswap(unsigned& a, unsigned& b) {
    auto r = __builtin_amdgcn_permlane32_swap(a, b, false, false);
    a = (unsigned)r[0];  // {a lanes 0-31, b lanes 0-31}
    b = (unsigned)r[1];  // {a lanes 32-63, b lanes 32-63}
}
static __device__ __forceinline__ unsigned pk2(float x, float y) {  // RTZ pack
    half2v h = __builtin_amdgcn_cvt_pkrtz(x, y);
    return __builtin_bit_cast(unsigned, h);
}
static __device__ __forceinline__ unsigned pk2rn(float x, float y) {  // RNE
    _Float16 hx = (_Float16)x, hy = (_Float16)y;
    unsigned short ux = __builtin_bit_cast(unsigned short, hx);
    unsigned short uy = __builtin_bit_cast(unsigned short, hy);
    return (unsigned)ux | ((unsigned)uy << 16);
}
static __device__ __forceinline__ float2 unpk(unsigned w) {
    half2v h = __builtin_bit_cast(half2v, w);
    return make_float2((float)h[0], (float)h[1]);
}

// fp32 plane: S[p][q] at p*64 + ((q + 4*(p&7)) & 63); quads 16B-aligned,
// never straddling the mod-64 wrap (q0 multiple of 4).
static __device__ __forceinline__ float4 ld4(const float* pl, int p, int q0) {
    int idx = (p << 6) + ((q0 + ((p & 7) << 2)) & 63);
    return *(const float4*)(pl + idx);
}

// C-acc tile half b -> hi/lo f16 A/B-frag (A==B frag via symmetry).
static __device__ __forceinline__ void split_frag(const facc& a, int b,
                                                  hfrag& fh, hfrag& fl) {
    unsigned Ph[2][2], Pl[2][2];  // [h_sub][pair]
#pragma unroll
    for (int hs = 0; hs < 2; ++hs)
#pragma unroll
        for (int p = 0; p < 2; ++p) {
            int r0 = ((hs + 2 * b) << 2) + (p << 1);
            float x = a[r0], y = a[r0 + 1];
            unsigned hw = pk2(x, y);
            float2 r = unpk(hw);
            Ph[hs][p] = hw;
            Pl[hs][p] = pk2(x - r.x, y - r.y);  // exact remainder in f16
        }
#pragma unroll
    for (int p = 0; p < 2; ++p) {
        plswap(Ph[0][p], Ph[1][p]);  // Ph[0]=elems e<4, Ph[1]=elems e>=4
        plswap(Pl[0][p], Pl[1][p]);
    }
    uint4v uh, ul;
    uh[0] = Ph[0][0]; uh[1] = Ph[0][1]; uh[2] = Ph[1][0]; uh[3] = Ph[1][1];
    ul[0] = Pl[0][0]; ul[1] = Pl[0][1]; ul[2] = Pl[1][0]; ul[3] = Pl[1][1];
    fh = __builtin_bit_cast(hfrag, uh);
    fl = __builtin_bit_cast(hfrag, ul);
}

// Single RNE-rounded f16 frag of a C-acc tile half (for W2).
static __device__ __forceinline__ hfrag round_frag(const facc& a, int b) {
    unsigned Ph[2][2];
#pragma unroll
    for (int hs = 0; hs < 2; ++hs)
#pragma unroll
        for (int p = 0; p < 2; ++p) {
            int r0 = ((hs + 2 * b) << 2) + (p << 1);
            Ph[hs][p] = pk2rn(a[r0], a[r0 + 1]);
        }
    plswap(Ph[0][0], Ph[1][0]);
    plswap(Ph[0][1], Ph[1][1]);
    uint4v u;
    u[0] = Ph[0][0]; u[1] = Ph[0][1]; u[2] = Ph[1][0]; u[3] = Ph[1][1];
    return __builtin_bit_cast(hfrag, u);
}

// q_s at this wave's C-layout positions: kw*w + kI*I (diag via one-hot dvec).
static __device__ __forceinline__ facc qs_init(const float* w32,
                                               const float (&dvec)[16],
                                               int ln, int h, int ti, int tj,
                                               float kI, float kw) {
    facc d;
    int col = (tj << 5) + ln;
#pragma unroll
    for (int qd = 0; qd < 4; ++qd) {
        int qb = (ti << 5) + (qd << 3) + (h << 2);
        float4 v = ld4(w32, col, qb);  // w[qb+k][col] via symmetry
        float e4[4] = {v.x, v.y, v.z, v.w};
#pragma unroll
        for (int k = 0; k < 4; ++k) {
            float b = kw * e4[k];
            if (ti == tj) b = fmaf(kI, dvec[(qd << 2) + k], b);
            d[(qd << 2) + k] = b;
        }
    }
    return d;
}

__global__ void __launch_bounds__(64, 2)
logeig_mfma_kernel(const float* __restrict__ in, float* __restrict__ out) {
    // monomial coeffs of deg-11 Chebyshev fit of log on [0.9, 8.5] in w
    constexpr float Bc[12] = {1.547606f,  0.808267f,  -0.329629f, 0.182560f,
                              -0.077085f, 0.022485f,  -0.158573f, 0.172463f,
                              0.154589f,  -0.173671f, -0.119491f, 0.110580f};

    __shared__ __align__(16) float w32[4096];  // 16 KB fp32 w plane

    const int l  = threadIdx.x;
    const int h  = l >> 5;
    const int ln = l & 31;

    const size_t mat = blockIdx.x;
    const float* g  = in  + (mat << 12);
    float*       go = out + (mat << 12);

    // one-hot diag selector per acc reg (row-in-tile == col-in-tile)
    float dvec[16];
#pragma unroll
    for (int reg = 0; reg < 16; ++reg) {
        int row = (reg & 3) + ((reg >> 2) << 3) + (h << 2);
        dvec[reg] = (row == ln) ? 1.0f : 0.0f;
    }

    // ---- P0: load M (coalesced float4), w = (M - 4.7 I)/3.8 -> fp32 plane.
#pragma unroll
    for (int rep = 0; rep < 16; ++rep) {
        int f = l + (rep << 6);
        int r = f >> 4, c4 = (f & 15) << 2;
        float4 v = ((const float4*)g)[f];
        float4 wv;
        wv.x = (v.x - ((r == c4 + 0) ? 4.7f : 0.0f)) * (1.0f / 3.8f);
        wv.y = (v.y - ((r == c4 + 1) ? 4.7f : 0.0f)) * (1.0f / 3.8f);
        wv.z = (v.z - ((r == c4 + 2) ? 4.7f : 0.0f)) * (1.0f / 3.8f);
        wv.w = (v.w - ((r == c4 + 3) ? 4.7f : 0.0f)) * (1.0f / 3.8f);
        int idx = (r << 6) + ((c4 + ((r & 7) << 2)) & 63);
        *(float4*)(w32 + idx) = wv;
    }
    __syncthreads();  // single-wave block: just orders LDS

    // ---- w frags (hi/lo f16) for P1.
    hfrag wfh[2][4], wfl[2][4];
#pragma unroll
    for (int t = 0; t < 2; ++t)
#pragma unroll
        for (int kb = 0; kb < 4; ++kb) {
            int row = (t << 5) + ln, q0 = (kb << 4) + (h << 3);
            float4 v0 = ld4(w32, row, q0);
            float4 v1 = ld4(w32, row, q0 + 4);
            float e[8] = {v0.x, v0.y, v0.z, v0.w, v1.x, v1.y, v1.z, v1.w};
            uint4v uh, ul;
#pragma unroll
            for (int j = 0; j < 4; ++j) {
                unsigned hw = pk2(e[2 * j], e[2 * j + 1]);
                float2 r = unpk(hw);
                uh[j] = hw;
                ul[j] = pk2(e[2 * j] - r.x, e[2 * j + 1] - r.y);
            }
            wfh[t][kb] = __builtin_bit_cast(hfrag, uh);
            wfl[t][kb] = __builtin_bit_cast(hfrag, ul);
        }

    // ---- P1: W2 = w*w (hh + hl + lh -> near-exact, exactly symmetric).
    facc c[2][2];
#pragma unroll
    for (int ti = 0; ti < 2; ++ti)
#pragma unroll
        for (int tj = 0; tj < 2; ++tj) c[ti][tj] = (facc)0.0f;
    __builtin_amdgcn_s_setprio(1);
#pragma unroll
    for (int kb = 0; kb < 4; ++kb)
#pragma unroll
        for (int ti = 0; ti < 2; ++ti) {
            hfrag ah = wfh[ti][kb], al = wfl[ti][kb];
#pragma unroll
            for (int tj = 0; tj < 2; ++tj) {
                c[ti][tj] = MFMA(ah, wfh[tj][kb], c[ti][tj]);
                c[ti][tj] = MFMA(ah, wfl[tj][kb], c[ti][tj]);
                c[ti][tj] = MFMA(al, wfh[tj][kb], c[ti][tj]);
            }
        }
    __builtin_amdgcn_s_setprio(0);

    // ---- W2 B-frags: single RNE f16, persistent (32 VGPR).
    hfrag W2f[2][4];
#pragma unroll
    for (int kb = 0; kb < 4; ++kb)
#pragma unroll
        for (int tj = 0; tj < 2; ++tj)
            W2f[tj][kb] = round_frag(c[kb >> 1][tj], kb & 1);

    // ---- T = q5 = Bc[10] I + Bc[11] w.
    facc T[2][2];
#pragma unroll
    for (int ti = 0; ti < 2; ++ti)
#pragma unroll
        for (int tj = 0; tj < 2; ++tj)
            T[ti][tj] = qs_init(w32, dvec, ln, h, ti, tj, Bc[10], Bc[11]);

    // ---- Horner s=4..0: d = q_s + T*W2, 2 MFMA/product (th,tl x W2f).
#pragma unroll
    for (int s = 4; s >= 0; --s) {
        const float kI = Bc[2 * s], kw = Bc[2 * s + 1];
        // A-frags from T via symmetry (T then dead until overwritten)
        hfrag th[2][4], tl[2][4];
#pragma unroll
        for (int kb = 0; kb < 4; ++kb)
#pragma unroll
            for (int ti = 0; ti < 2; ++ti)
                split_frag(T[kb >> 1][ti], kb & 1, th[ti][kb], tl[ti][kb]);
        facc d[2][2];
#pragma unroll
        for (int ti = 0; ti < 2; ++ti)
#pragma unroll
            for (int tj = 0; tj < 2; ++tj)
                d[ti][tj] = qs_init(w32, dvec, ln, h, ti, tj, kI, kw);
        __builtin_amdgcn_s_setprio(1);
#pragma unroll
        for (int kb = 0; kb < 4; ++kb)
#pragma unroll
            for (int ti = 0; ti < 2; ++ti)
#pragma unroll
                for (int tj = 0; tj < 2; ++tj) {
                    d[ti][tj] = MFMA(th[ti][kb], W2f[tj][kb], d[ti][tj]);
                    d[ti][tj] = MFMA(tl[ti][kb], W2f[tj][kb], d[ti][tj]);
                }
        __builtin_amdgcn_s_setprio(0);
        if (s > 0) {
#pragma unroll
            for (int ti = 0; ti < 2; ++ti)
#pragma unroll
                for (int tj = 0; tj < 2; ++tj) T[ti][tj] = d[ti][tj];
        } else {
            // out = T: C-layout straight to global (two 128B segments/instr)
#pragma unroll
            for (int ti = 0; ti < 2; ++ti)
#pragma unroll
                for (int tj = 0; tj < 2; ++tj)
#pragma unroll
                    for (int reg = 0; reg < 16; ++reg) {
                        int row = (ti << 5) + (reg & 3) + ((reg >> 2) << 3) + (h << 2);
                        go[(row << 6) + (tj << 5) + ln] = d[ti][tj][reg];
                    }
        }
    }
}

extern "C" void kernel_launch(void* const* d_in, const int* in_sizes, int n_in,
                              void* d_out, int out_size, void* d_ws, size_t ws_size,
                              hipStream_t stream) {
    const float* in = (const float*)d_in[0];
    float* out = (float*)d_out;
    const int batch = in_sizes[0] >> 12;  // 8192 matrices of 64x64
    hipLaunchKernelGGL(logeig_mfma_kernel, dim3(batch), dim3(64), 0,
                       stream, in, out);
}